// Round 5
// baseline (164.505 us; speedup 1.0000x reference)
//
#include <hip/hip_runtime.h>

// Problem constants: B=64, I=512, H=1024, D=I+H=1536
constexpr int Bn = 64;
constexpr int In = 512;
constexpr int Hn = 1024;
constexpr int Dn = 1536;
constexpr float ALPHA = 0.001f;
constexpr int RPW = 16;                // rows per wave (all 64 b per block)

// Native 4-float vector for __builtin_nontemporal_store.
typedef float nfloat4 __attribute__((ext_vector_type(4)));

// Block = one k, all 64 b. 1024 blocks x 256 threads.
//  - Wa..Wd[k,:] staged to LDS once (24 KB), amortized over 64 rows.
//  - Each wave owns 16 rows. wih (the HBM stream) is prefetched 2 rows deep
//    via 3 rotating register buffers; x (L2-hot) is loaded per-row, issued
//    BEFORE the next wih prefetch so waiting on x never drains wih loads.
//  - __launch_bounds__(256,4) caps VGPR at 128 -> 4 waves/SIMD, 16 waves/CU
//    (R4 post-mortem: deep buffers at ~180 VGPR halved occupancy and the
//    lost TLP cancelled the ILP gain).
__global__ __launch_bounds__(256, 4) void prnn_fused_kernel(
    const float* __restrict__ inputs,   // B x I
    const float* __restrict__ hidden,   // B x H
    const float* __restrict__ wih,      // B x H x D
    const float* __restrict__ Wa,       // H x D
    const float* __restrict__ Wb,       // H x D
    const float* __restrict__ Wc,       // H x D
    const float* __restrict__ Wd,       // H x D
    const float* __restrict__ bih,      // H
    float* __restrict__ out_hidden,     // B x H
    float* __restrict__ out_wih)        // B x H x D
{
    __shared__ float4 sW[4 * (Dn / 4)];   // 24 KB

    const int k   = blockIdx.x;
    const int tid = threadIdx.x;

    // Cooperative LDS stage of Wa..Wd row k (384 float4 per tensor).
    {
        const float4* wa4 = (const float4*)(Wa + (size_t)k * Dn);
        const float4* wb4 = (const float4*)(Wb + (size_t)k * Dn);
        const float4* wc4 = (const float4*)(Wc + (size_t)k * Dn);
        const float4* wd4 = (const float4*)(Wd + (size_t)k * Dn);
        #pragma unroll
        for (int e = 0; e < 2; ++e) {
            const int i = tid + e * 256;
            if (i < 384) {
                sW[i]        = wa4[i];
                sW[384 + i]  = wb4[i];
                sW[768 + i]  = wc4[i];
                sW[1152 + i] = wd4[i];
            }
        }
    }
    __syncthreads();

    const int wave = tid >> 6;
    const int lane = tid & 63;
    const int b0   = wave * RPW;
    const float bk = bih[k];
    const int base = lane * 4;

    float4 wbuf[3][6];   // wih: 2-row-deep prefetch (3 rotating buffers)
    float4 x[6];         // x: loaded per-row (L2-hot, ~250 cyc, TLP-covered)

    auto load_w = [&](int r, float4 (&w)[6]) {
        const float* __restrict__ wrow = wih + ((size_t)(b0 + r) * Hn + k) * Dn;
        #pragma unroll
        for (int c = 0; c < 6; ++c)
            w[c] = *(const float4*)(wrow + c * 256 + base);
    };

    // Prologue: 2 rows of wih in flight.
    load_w(0, wbuf[0]);
    load_w(1, wbuf[1]);

    #pragma unroll
    for (int r = 0; r < RPW; ++r) {     // fully unrolled: static buffer indices
        const int b = b0 + r;

        // Issue x loads FIRST (so the wait for x leaves wih prefetch in flight)...
        {
            const float* __restrict__ xin  = inputs + b * In;
            const float* __restrict__ xhid = hidden + b * Hn;
            #pragma unroll
            for (int c = 0; c < 6; ++c) {
                const int idx = c * 256 + base;
                x[c] = (c < 2) ? *(const float4*)(xin + idx)
                               : *(const float4*)(xhid + (idx - In));
            }
        }
        // ...then the next wih prefetch.
        if (r + 2 < RPW) load_w(r + 2, wbuf[(r + 2) % 3]);

        float4 (&w)[6] = wbuf[r % 3];

        float acc = 0.0f;
        #pragma unroll
        for (int c = 0; c < 6; ++c)
            acc += w[c].x * x[c].x + w[c].y * x[c].y
                 + w[c].z * x[c].z + w[c].w * x[c].w;

        #pragma unroll
        for (int off = 32; off > 0; off >>= 1)
            acc += __shfl_xor(acc, off, 64);

        const float y = tanhf(acc + bk);
        if (lane == 0) out_hidden[b * Hn + k] = y;

        float* __restrict__ orow = out_wih + ((size_t)b * Hn + k) * Dn;
        #pragma unroll
        for (int c = 0; c < 6; ++c) {
            const int e = c * 64 + lane;
            const float4 a4 = sW[e];
            const float4 b4 = sW[384 + e];
            const float4 c4 = sW[768 + e];
            const float4 d4 = sW[1152 + e];
            nfloat4 o;
            o.x = w[c].x + ALPHA * (y * x[c].x * a4.x + x[c].x * b4.x + y * c4.x + d4.x);
            o.y = w[c].y + ALPHA * (y * x[c].y * a4.y + x[c].y * b4.y + y * c4.y + d4.y);
            o.z = w[c].z + ALPHA * (y * x[c].z * a4.z + x[c].z * b4.z + y * c4.z + d4.z);
            o.w = w[c].w + ALPHA * (y * x[c].w * a4.w + x[c].w * b4.w + y * c4.w + d4.w);
            __builtin_nontemporal_store(o, (nfloat4*)(orow + c * 256 + base));
        }
    }
}

extern "C" void kernel_launch(void* const* d_in, const int* in_sizes, int n_in,
                              void* d_out, int out_size, void* d_ws, size_t ws_size,
                              hipStream_t stream) {
    const float* inputs = (const float*)d_in[0];
    const float* hidden = (const float*)d_in[1];
    const float* wih    = (const float*)d_in[2];
    const float* Wa     = (const float*)d_in[3];
    const float* Wb     = (const float*)d_in[4];
    const float* Wc     = (const float*)d_in[5];
    const float* Wd     = (const float*)d_in[6];
    const float* bih    = (const float*)d_in[7];
    // d_in[8] = W_dop, d_in[9] = b_dop feed only _dopamine (not returned) -> skipped.

    float* out_hidden = (float*)d_out;                    // B*H floats
    float* out_wih    = (float*)d_out + (size_t)Bn * Hn;  // B*H*D floats

    prnn_fused_kernel<<<dim3(Hn), dim3(256), 0, stream>>>(
        inputs, hidden, wih, Wa, Wb, Wc, Wd, bih, out_hidden, out_wih);
}